// Round 6
// baseline (463.411 us; speedup 1.0000x reference)
//
#include <hip/hip_runtime.h>
#include <cstdint>
#include <cstddef>

// EEGFormer block on MI355X. N=32768 tokens, L=512, H=8 heads of D=64, C=256 region.
#define NTOK 32768
#define LDIM 512
#define HN 8
#define HD 64
#define CC 256
#define FFD 2048

typedef __bf16 bf16x8 __attribute__((ext_vector_type(8)));
typedef float f32x4 __attribute__((ext_vector_type(4)));
typedef unsigned short u16;
typedef unsigned int u32;

__device__ __forceinline__ u16 f2bf(float f) {
  u32 u = __float_as_uint(f);
  u32 r = (u + 0x7fffu + ((u >> 16) & 1u)) >> 16;  // RNE
  return (u16)r;
}

__device__ __forceinline__ void gload_lds16(const void* g, void* l) {
  __builtin_amdgcn_global_load_lds(
      (__attribute__((address_space(1))) void*)(void*)g,
      (__attribute__((address_space(3))) void*)l, 16, 0, 0);
}

// ---------------- f32 -> bf16 convert (all weights, one launch) ----------------
__global__ void k_convall(const float* __restrict__ Wq, const float* __restrict__ Wk,
                          const float* __restrict__ Wv, const float* __restrict__ Wo,
                          const float* __restrict__ W1, const float* __restrict__ W2,
                          u16* __restrict__ wqkv, u16* __restrict__ wo,
                          u16* __restrict__ w1, u16* __restrict__ w2) {
  const int NW = 262144;            // 512*512
  const int MW = 1048576;           // 2048*512
  const int TOT = 4 * NW + 2 * MW;  // 3145728
  int i = blockIdx.x * blockDim.x + threadIdx.x;
  const int st = gridDim.x * blockDim.x;
  for (; i < TOT; i += st) {
    if (i < NW) wqkv[i] = f2bf(Wq[i]);
    else if (i < 2 * NW) wqkv[i] = f2bf(Wk[i - NW]);
    else if (i < 3 * NW) wqkv[i] = f2bf(Wv[i - 2 * NW]);
    else if (i < 4 * NW) wo[i - 3 * NW] = f2bf(Wo[i - 3 * NW]);
    else if (i < 4 * NW + MW) w1[i - 4 * NW] = f2bf(W1[i - 4 * NW]);
    else w2[i - 4 * NW - MW] = f2bf(W2[i - 4 * NW - MW]);
  }
}

// ---------------- LayerNorm (f32 in -> bf16 out), 1 wave per row ----------------
__global__ __launch_bounds__(256) void k_ln(const float* __restrict__ x,
                                            const float* __restrict__ gam,
                                            const float* __restrict__ bet,
                                            u16* __restrict__ out) {
  const int row = blockIdx.x * 4 + (threadIdx.x >> 6);
  const int lane = threadIdx.x & 63;
  const float4* xr = (const float4*)(x + (size_t)row * LDIM);
  float4 a = xr[lane * 2], b = xr[lane * 2 + 1];
  float s = a.x + a.y + a.z + a.w + b.x + b.y + b.z + b.w;
  float q = a.x * a.x + a.y * a.y + a.z * a.z + a.w * a.w +
            b.x * b.x + b.y * b.y + b.z * b.z + b.w * b.w;
#pragma unroll
  for (int m = 1; m < 64; m <<= 1) { s += __shfl_xor(s, m); q += __shfl_xor(q, m); }
  const float mean = s * (1.f / LDIM);
  const float rs = rsqrtf(q * (1.f / LDIM) - mean * mean + 1e-5f);
  const int c0 = lane * 8;
  const float4* g4 = (const float4*)(gam + c0);
  const float4* b4 = (const float4*)(bet + c0);
  float4 ga = g4[0], gb = g4[1], ba = b4[0], bb = b4[1];
  float vin[8] = {a.x, a.y, a.z, a.w, b.x, b.y, b.z, b.w};
  float vg[8]  = {ga.x, ga.y, ga.z, ga.w, gb.x, gb.y, gb.z, gb.w};
  float vb[8]  = {ba.x, ba.y, ba.z, ba.w, bb.x, bb.y, bb.z, bb.w};
  u16 o[8];
#pragma unroll
  for (int i = 0; i < 8; ++i) o[i] = f2bf((vin[i] - mean) * rs * vg[i] + vb[i]);
  *(bf16x8*)(out + (size_t)row * LDIM + c0) = *(bf16x8*)o;
}

// ---------------- 8-phase 256x256 GEMM (m201-shape): C = A[M,K]*Bw[N,K]^T ----------------
// 8 waves (2Mx4N), BK=64/K-tile, 4 phases/tile, 16 MFMA/phase.
// Phase: {ds_read frags (published data); stage 1 half (2 gload_lds); [vmcnt];
//         s_barrier; lgkmcnt(0); sched_barrier(0); setprio(1) MFMAx16 setprio(0); s_barrier}
// Half-stream h=4T+{0:Akh0,1:Bkh0,2:Akh1,3:Bkh1}; phase P1..P4 of tile T stages
// h=4T+6,7,8,9 (lookahead 6 halves). Drains: vmcnt(8) at P2 & P4 (publishes the
// 2 halves the following reads need; 1 K-tile stays in flight). Tail: P4(NT-2)=vm4,
// P2(NT-1)=vm0. Prologue: stage h0..h5, vmcnt(8), barrier.
// Swizzle: LDS slot chunk c of row r holds global chunk c^((r>>1)&3); read same XOR.
// EPI: 0 bf16 store; 1 +bias+resid(f32)->f32; 2 relu(+bias)->bf16; 3 f32 out += acc+bias

__device__ __forceinline__ void stage_half(const u16* __restrict__ g, int K,
                                           u16* __restrict__ lds, int t) {
#pragma unroll
  for (int i = 0; i < 2; ++i) {
    const int p = i * 512 + t;
    const int r = p >> 2;
    const int c = ((p & 3) ^ ((r >> 1) & 3)) << 3;
    gload_lds16(g + (size_t)r * K + c, lds + ((i * 512 + (t & ~63)) << 3));
  }
}

__device__ __forceinline__ bf16x8 ldsfrag(const u16* __restrict__ s, int R, int kq) {
  return *(const bf16x8*)(s + R * 32 + ((kq ^ ((R >> 1) & 3)) << 3));
}

#define VM8 asm volatile("s_waitcnt vmcnt(8)" ::: "memory")
#define VM4 asm volatile("s_waitcnt vmcnt(4)" ::: "memory")
#define VM0 asm volatile("s_waitcnt vmcnt(0)" ::: "memory")
#define LGKM0 asm volatile("s_waitcnt lgkmcnt(0)" ::: "memory")
#define BARRIER asm volatile("s_barrier" ::: "memory")

template <int EPI>
__global__ __launch_bounds__(512, 2) void k_gemm8(const u16* __restrict__ A,
                                                  const u16* __restrict__ Bw, int K,
                                                  const float* __restrict__ bias,
                                                  const float* __restrict__ resid,
                                                  void* __restrict__ outp, int ldc,
                                                  int bmN) {
  extern __shared__ u16 lds_g[];
  const int t = threadIdx.x;
  const int lane = t & 63;
  const int w = t >> 6;
  const int wm = w >> 2, wn = w & 3;  // 2 x 4 waves, wave tile 128x64
  const int rl = lane & 15;
  const int kq = lane >> 4;
  // XCD-chunked block swizzle (grid %8==0 for all launches)
  const int nwg = gridDim.x;
  const int cpx = nwg >> 3;
  const int id = blockIdx.x;
  const int sid = (id & 7) * cpx + (id >> 3);
  const int bm = sid % bmN, bn = sid / bmN;

  const u16* Ag = A + (size_t)bm * 256 * K;
  const u16* Bg = Bw + (size_t)bn * 256 * K;
  u16* SA0 = lds_g;
  u16* SB0 = lds_g + 32768;
#define SA(par, kh) (SA0 + (par) * 16384 + (kh) * 8192)
#define SB(par, kh) (SB0 + (par) * 16384 + (kh) * 8192)

  f32x4 acc[8][4] = {};

  // prologue: halves h0..h5 = T0{A0,B0,A1,B1}, T1{A0,B0}
  stage_half(Ag, K, SA(0, 0), t);
  stage_half(Bg, K, SB(0, 0), t);
  stage_half(Ag + 32, K, SA(0, 1), t);
  stage_half(Bg + 32, K, SB(0, 1), t);
  stage_half(Ag + 64, K, SA(1, 0), t);
  stage_half(Bg + 64, K, SB(1, 0), t);
  VM8;
  BARRIER;

  const int NT = K >> 6;
  const int rA = wm * 128 + rl;
  const int rB = wn * 64 + rl;

#define MFMA16(ACCBASE)                                                          \
  LGKM0;                                                                         \
  __builtin_amdgcn_sched_barrier(0);                                             \
  __builtin_amdgcn_s_setprio(1);                                                 \
  _Pragma("unroll") for (int f = 0; f < 4; ++f)                                  \
      _Pragma("unroll") for (int n = 0; n < 4; ++n)                              \
          acc[(ACCBASE) + f][n] =                                                \
              __builtin_amdgcn_mfma_f32_16x16x32_bf16(a[f], b[n],                \
                                                      acc[(ACCBASE) + f][n],     \
                                                      0, 0, 0);                  \
  __builtin_amdgcn_s_setprio(0);                                                 \
  BARRIER

  for (int T = 0; T < NT; ++T) {
    const int par = T & 1, nx = par ^ 1;
    bf16x8 a[4], b[4];
    // ---- P1: read A0,B0(T); stage (T+1,A1); MFMA acc[0..3] ----
    {
      const u16* s = SA(par, 0);
#pragma unroll
      for (int f = 0; f < 4; ++f) a[f] = ldsfrag(s, rA + f * 16, kq);
      const u16* sb = SB(par, 0);
#pragma unroll
      for (int n = 0; n < 4; ++n) b[n] = ldsfrag(sb, rB + n * 16, kq);
      if (T + 1 < NT) stage_half(Ag + (size_t)(T + 1) * 64 + 32, K, SA(nx, 1), t);
      BARRIER;
      MFMA16(0);
    }
    // ---- P2: read A0 upper; stage (T+1,B1); vm drain; MFMA acc[4..7] ----
    {
      const u16* s = SA(par, 0);
#pragma unroll
      for (int f = 0; f < 4; ++f) a[f] = ldsfrag(s, rA + 64 + f * 16, kq);
      if (T + 1 < NT) stage_half(Bg + (size_t)(T + 1) * 64 + 32, K, SB(nx, 1), t);
      if (T < NT - 1) { VM8; } else { VM0; }
      BARRIER;
      MFMA16(4);
    }
    // ---- P3: read A1,B1(T); stage (T+2,A0); MFMA acc[0..3] ----
    {
      const u16* s = SA(par, 1);
#pragma unroll
      for (int f = 0; f < 4; ++f) a[f] = ldsfrag(s, rA + f * 16, kq);
      const u16* sb = SB(par, 1);
#pragma unroll
      for (int n = 0; n < 4; ++n) b[n] = ldsfrag(sb, rB + n * 16, kq);
      if (T + 2 < NT) stage_half(Ag + (size_t)(T + 2) * 64, K, SA(par, 0), t);
      BARRIER;
      MFMA16(0);
    }
    // ---- P4: read A1 upper; stage (T+2,B0); vm drain; MFMA acc[4..7] ----
    {
      const u16* s = SA(par, 1);
#pragma unroll
      for (int f = 0; f < 4; ++f) a[f] = ldsfrag(s, rA + 64 + f * 16, kq);
      if (T + 2 < NT) stage_half(Bg + (size_t)(T + 2) * 64, K, SB(par, 0), t);
      if (T < NT - 2) { VM8; } else if (T == NT - 2) { VM4; }
      BARRIER;
      MFMA16(4);
    }
  }
#undef SA
#undef SB
#undef MFMA16

  // epilogue: D layout col=lane&15, row=4*(lane>>4)+reg (m89-verified)
  const int rg = (lane >> 4) * 4;
  const int cl = lane & 15;
#pragma unroll
  for (int mi = 0; mi < 8; ++mi)
#pragma unroll
    for (int n = 0; n < 4; ++n) {
      const int mg = bm * 256 + wm * 128 + mi * 16 + rg;
      const int og = bn * 256 + wn * 64 + n * 16 + cl;
#pragma unroll
      for (int r = 0; r < 4; ++r) {
        float v = acc[mi][n][r];
        size_t idx = (size_t)(mg + r) * ldc + og;
        if (EPI == 0) {
          ((u16*)outp)[idx] = f2bf(v);
        } else if (EPI == 1) {
          ((float*)outp)[idx] = resid[idx] + v + bias[og];
        } else if (EPI == 2) {
          ((u16*)outp)[idx] = f2bf(fmaxf(v + bias[og], 0.f));
        } else {
          ((float*)outp)[idx] = ((float*)outp)[idx] + v + bias[og];
        }
      }
    }
}

// ---------------- Attention: one block per (region, head); 4 waves x 64 q-rows ----------------
__device__ __forceinline__ int swz(int row, int col) {
  return row * 64 + (col ^ ((row & 7) << 3));
}

__global__ __launch_bounds__(256) void k_attn(const u16* __restrict__ qkv,
                                              u16* __restrict__ attn) {
  __shared__ u16 Ks[64 * 64];
  __shared__ u16 Vt[64 * 64];
  __shared__ u16 Pl[4 * 64 * 64];
  const int t = threadIdx.x, lane = t & 63, w = t >> 6;
  const int region = blockIdx.x >> 3;
  const int h = blockIdx.x & 7;
  const size_t n0 = (size_t)region * CC;
  const int qb = w * 64;
  const int rl = lane & 15;
  const int kg = (lane >> 4) * 8;
  u16* Pw = Pl + w * 4096;

  bf16x8 aq[4][2];
#pragma unroll
  for (int f = 0; f < 4; ++f)
#pragma unroll
    for (int ks = 0; ks < 2; ++ks)
      aq[f][ks] = *(const bf16x8*)&qkv[(n0 + qb + f * 16 + rl) * 1536 + h * 64 + ks * 32 + kg];

  f32x4 oacc[4][4] = {};
  float mrun[4][4], lrun[4][4];
#pragma unroll
  for (int i = 0; i < 4; ++i)
#pragma unroll
    for (int j = 0; j < 4; ++j) { mrun[i][j] = -1e30f; lrun[i][j] = 0.f; }

  const int sr = t >> 2;
  const int sc = (t & 3) * 16;
  for (int kt = 0; kt < 4; ++kt) {
    if (kt) __syncthreads();
    {
      const u16* kp = &qkv[(n0 + kt * 64 + sr) * 1536 + 512 + h * 64 + sc];
      bf16x8 k0 = *(const bf16x8*)kp;
      bf16x8 k1 = *(const bf16x8*)(kp + 8);
      *(bf16x8*)&Ks[swz(sr, sc)] = k0;
      *(bf16x8*)&Ks[swz(sr, sc + 8)] = k1;
      const u16* vp = &qkv[(n0 + kt * 64 + sr) * 1536 + 1024 + h * 64 + sc];
      bf16x8 v0 = *(const bf16x8*)vp;
      bf16x8 v1 = *(const bf16x8*)(vp + 8);
#pragma unroll
      for (int i = 0; i < 8; ++i) Vt[swz(sc + i, sr)] = ((u16*)&v0)[i];
#pragma unroll
      for (int i = 0; i < 8; ++i) Vt[swz(sc + 8 + i, sr)] = ((u16*)&v1)[i];
    }
    __syncthreads();
    f32x4 sacc[4][4] = {};
#pragma unroll
    for (int ks = 0; ks < 2; ++ks) {
      bf16x8 bk[4];
#pragma unroll
      for (int f = 0; f < 4; ++f) bk[f] = *(const bf16x8*)&Ks[swz(f * 16 + rl, ks * 32 + kg)];
#pragma unroll
      for (int i = 0; i < 4; ++i)
#pragma unroll
        for (int j = 0; j < 4; ++j)
          sacc[i][j] = __builtin_amdgcn_mfma_f32_16x16x32_bf16(aq[i][ks], bk[j], sacc[i][j], 0, 0, 0);
    }
#pragma unroll
    for (int i = 0; i < 4; ++i)
#pragma unroll
      for (int j = 0; j < 4; ++j)
#pragma unroll
        for (int r = 0; r < 4; ++r) sacc[i][j][r] *= 0.125f;
#pragma unroll
    for (int i = 0; i < 4; ++i) {
#pragma unroll
      for (int r = 0; r < 4; ++r) {
        float v = fmaxf(fmaxf(sacc[i][0][r], sacc[i][1][r]), fmaxf(sacc[i][2][r], sacc[i][3][r]));
#pragma unroll
        for (int m = 1; m < 16; m <<= 1) v = fmaxf(v, __shfl_xor(v, m));
        float mnew = fmaxf(mrun[i][r], v);
        float fac = __expf(mrun[i][r] - mnew);
        mrun[i][r] = mnew;
        float ps = 0.f;
#pragma unroll
        for (int fn = 0; fn < 4; ++fn) {
          float p = __expf(sacc[i][fn][r] - mnew);
          sacc[i][fn][r] = p;
          ps += p;
        }
#pragma unroll
        for (int m = 1; m < 16; m <<= 1) ps += __shfl_xor(ps, m);
        lrun[i][r] = lrun[i][r] * fac + ps;
#pragma unroll
        for (int fd = 0; fd < 4; ++fd) oacc[i][fd][r] *= fac;
      }
#pragma unroll
      for (int fn = 0; fn < 4; ++fn)
#pragma unroll
        for (int r = 0; r < 4; ++r)
          Pw[swz(i * 16 + (lane >> 4) * 4 + r, fn * 16 + rl)] = f2bf(sacc[i][fn][r]);
    }
#pragma unroll
    for (int ks = 0; ks < 2; ++ks) {
      bf16x8 ap[4], bv[4];
#pragma unroll
      for (int f = 0; f < 4; ++f) ap[f] = *(const bf16x8*)&Pw[swz(f * 16 + rl, ks * 32 + kg)];
#pragma unroll
      for (int f = 0; f < 4; ++f) bv[f] = *(const bf16x8*)&Vt[swz(f * 16 + rl, ks * 32 + kg)];
#pragma unroll
      for (int i = 0; i < 4; ++i)
#pragma unroll
        for (int j = 0; j < 4; ++j)
          oacc[i][j] = __builtin_amdgcn_mfma_f32_16x16x32_bf16(ap[i], bv[j], oacc[i][j], 0, 0, 0);
    }
  }
#pragma unroll
  for (int i = 0; i < 4; ++i)
#pragma unroll
    for (int fd = 0; fd < 4; ++fd)
#pragma unroll
      for (int r = 0; r < 4; ++r) {
        float v = oacc[i][fd][r] / lrun[i][r];
        attn[(n0 + qb + i * 16 + (lane >> 4) * 4 + r) * 512 + h * 64 + fd * 16 + rl] = f2bf(v);
      }
}

// ---------------- host launch ----------------
extern "C" void kernel_launch(void* const* d_in, const int* in_sizes, int n_in,
                              void* d_out, int out_size, void* d_ws, size_t ws_size,
                              hipStream_t stream) {
  (void)in_sizes; (void)n_in; (void)out_size; (void)ws_size;
  const float* x   = (const float*)d_in[0];
  const float* Wq  = (const float*)d_in[1];
  const float* Wk  = (const float*)d_in[2];
  const float* Wv  = (const float*)d_in[3];
  const float* Wo  = (const float*)d_in[4];
  const float* bo  = (const float*)d_in[5];
  const float* W1  = (const float*)d_in[6];
  const float* b1  = (const float*)d_in[7];
  const float* W2  = (const float*)d_in[8];
  const float* b2  = (const float*)d_in[9];
  const float* g1  = (const float*)d_in[10];
  const float* be1 = (const float*)d_in[11];
  const float* g2  = (const float*)d_in[12];
  const float* be2 = (const float*)d_in[13];
  float* out = (float*)d_out;

  char* ws = (char*)d_ws;
  u16* wqkv = (u16*)(ws + 0);          // [1536][512] bf16
  u16* wo   = (u16*)(ws + 1572864);    // [512][512]
  u16* w1   = (u16*)(ws + 2097152);    // [2048][512]
  u16* w2   = (u16*)(ws + 4194304);    // [512][2048]
  u16* regA = (u16*)(ws + 6291456);    // [N][512] bf16: h / attn / h2
  u16* regB = (u16*)(ws + 39845888);   // [N][1536] qkv, then [N][2048] ff

  const size_t LDSB = 131072;  // 128KB dynamic LDS for k_gemm8

  k_convall<<<1024, 256, 0, stream>>>(Wq, Wk, Wv, Wo, W1, W2, wqkv, wo, w1, w2);
  k_ln<<<NTOK / 4, 256, 0, stream>>>(x, g1, be1, regA);
  // QKV: [32768x512] x [1536x512]^T -> [N][1536]
  k_gemm8<0><<<dim3(128 * 6), 512, LDSB, stream>>>(regA, wqkv, 512, nullptr, nullptr, regB, 1536, 128);
  k_attn<<<dim3(4 * 32 * 8), 256, 0, stream>>>(regB, regA);
  // proj + bias + residual(x) -> out (f32)
  k_gemm8<1><<<dim3(128 * 2), 512, LDSB, stream>>>(regA, wo, 512, bo, x, out, 512, 128);
  k_ln<<<NTOK / 4, 256, 0, stream>>>(out, g2, be2, regA);
  // FFN1: relu(h2 * w1^T + b1) -> [N][2048]
  k_gemm8<2><<<dim3(128 * 8), 512, LDSB, stream>>>(regA, w1, 512, b1, nullptr, regB, 2048, 128);
  // FFN2: out += ff * w2^T + b2
  k_gemm8<3><<<dim3(128 * 2), 512, LDSB, stream>>>(regB, w2, 2048, b2, nullptr, out, 512, 128);
}

// Round 7
// 448.127 us; speedup vs baseline: 1.0341x; 1.0341x over previous
//
#include <hip/hip_runtime.h>
#include <cstdint>
#include <cstddef>

// EEGFormer block on MI355X. N=32768 tokens, L=512, H=8 heads of D=64, C=256 region.
#define NTOK 32768
#define LDIM 512
#define HN 8
#define HD 64
#define CC 256
#define FFD 2048

typedef __bf16 bf16x8 __attribute__((ext_vector_type(8)));
typedef float f32x4 __attribute__((ext_vector_type(4)));
typedef unsigned short u16;
typedef unsigned int u32;

__device__ __forceinline__ u16 f2bf(float f) {
  u32 u = __float_as_uint(f);
  u32 r = (u + 0x7fffu + ((u >> 16) & 1u)) >> 16;  // RNE
  return (u16)r;
}

__device__ __forceinline__ void gload_lds16(const void* g, void* l) {
  __builtin_amdgcn_global_load_lds(
      (__attribute__((address_space(1))) void*)(void*)g,
      (__attribute__((address_space(3))) void*)l, 16, 0, 0);
}

// ---------------- f32 -> bf16 convert (all weights, one launch) ----------------
__global__ void k_convall(const float* __restrict__ Wq, const float* __restrict__ Wk,
                          const float* __restrict__ Wv, const float* __restrict__ Wo,
                          const float* __restrict__ W1, const float* __restrict__ W2,
                          u16* __restrict__ wqkv, u16* __restrict__ wo,
                          u16* __restrict__ w1, u16* __restrict__ w2) {
  const int NW = 262144;            // 512*512
  const int MW = 1048576;           // 2048*512
  const int TOT = 4 * NW + 2 * MW;  // 3145728
  int i = blockIdx.x * blockDim.x + threadIdx.x;
  const int st = gridDim.x * blockDim.x;
  for (; i < TOT; i += st) {
    if (i < NW) wqkv[i] = f2bf(Wq[i]);
    else if (i < 2 * NW) wqkv[i] = f2bf(Wk[i - NW]);
    else if (i < 3 * NW) wqkv[i] = f2bf(Wv[i - 2 * NW]);
    else if (i < 4 * NW) wo[i - 3 * NW] = f2bf(Wo[i - 3 * NW]);
    else if (i < 4 * NW + MW) w1[i - 4 * NW] = f2bf(W1[i - 4 * NW]);
    else w2[i - 4 * NW - MW] = f2bf(W2[i - 4 * NW - MW]);
  }
}

// ---------------- LayerNorm (f32 in -> bf16 out), 1 wave per row ----------------
__global__ __launch_bounds__(256) void k_ln(const float* __restrict__ x,
                                            const float* __restrict__ gam,
                                            const float* __restrict__ bet,
                                            u16* __restrict__ out) {
  const int row = blockIdx.x * 4 + (threadIdx.x >> 6);
  const int lane = threadIdx.x & 63;
  const float4* xr = (const float4*)(x + (size_t)row * LDIM);
  float4 a = xr[lane * 2], b = xr[lane * 2 + 1];
  float s = a.x + a.y + a.z + a.w + b.x + b.y + b.z + b.w;
  float q = a.x * a.x + a.y * a.y + a.z * a.z + a.w * a.w +
            b.x * b.x + b.y * b.y + b.z * b.z + b.w * b.w;
#pragma unroll
  for (int m = 1; m < 64; m <<= 1) { s += __shfl_xor(s, m); q += __shfl_xor(q, m); }
  const float mean = s * (1.f / LDIM);
  const float rs = rsqrtf(q * (1.f / LDIM) - mean * mean + 1e-5f);
  const int c0 = lane * 8;
  const float4* g4 = (const float4*)(gam + c0);
  const float4* b4 = (const float4*)(bet + c0);
  float4 ga = g4[0], gb = g4[1], ba = b4[0], bb = b4[1];
  float vin[8] = {a.x, a.y, a.z, a.w, b.x, b.y, b.z, b.w};
  float vg[8]  = {ga.x, ga.y, ga.z, ga.w, gb.x, gb.y, gb.z, gb.w};
  float vb[8]  = {ba.x, ba.y, ba.z, ba.w, bb.x, bb.y, bb.z, bb.w};
  u16 o[8];
#pragma unroll
  for (int i = 0; i < 8; ++i) o[i] = f2bf((vin[i] - mean) * rs * vg[i] + vb[i]);
  *(bf16x8*)(out + (size_t)row * LDIM + c0) = *(bf16x8*)o;
}

// ---------------- 8-phase 256x256 GEMM, M-split halves: C = A[M,K]*Bw[N,K]^T ----------------
// 8 waves (2Mx4N), BK=64/K-tile, 4 phases/tile, 16 MFMA/phase.
// LDS halves [128 rows][64 K] x {Ahi,Alo,Bhi,Blo} x 2 parity = 128KB.
// Swizzle: 16B chunk c of row r stored at slot c^(r&7); applied to pre-swizzled
// global source AND ds_read (involution; global stays fully 128B-coalesced).
// B-fragments are read ONCE per tile (P1) into registers (b[4][2]).
// Staging: P1 stages Ahi+Bhi(T+1), P2 stages Alo+Blo(T+1); single vmcnt(0)
// at end of P4 (~3 phases of slack vs ~900cy HBM latency).
// EPI: 0 bf16 store; 1 +bias+resid(f32)->f32; 2 relu(+bias)->bf16; 3 f32 out += acc+bias

__device__ __forceinline__ void stage_half128(const u16* __restrict__ g, int K,
                                              u16* __restrict__ lds, int t) {
#pragma unroll
  for (int i = 0; i < 2; ++i) {
    const int p = i * 512 + t;
    const int r = p >> 3;                    // row 0..127
    const int c = ((p & 7) ^ (r & 7)) << 3;  // swizzled 16B chunk -> elem offset
    gload_lds16(g + (size_t)r * K + c, lds + ((i * 512 + (t & ~63)) << 3));
  }
}

__device__ __forceinline__ bf16x8 ldsfrag64(const u16* __restrict__ s, int R, int ck) {
  return *(const bf16x8*)(s + R * 64 + ((ck ^ (R & 7)) << 3));
}

#define VM0 asm volatile("s_waitcnt vmcnt(0)" ::: "memory")
#define LGKM0 asm volatile("s_waitcnt lgkmcnt(0)" ::: "memory")
#define BARRIER asm volatile("s_barrier" ::: "memory")

template <int EPI>
__global__ __launch_bounds__(512, 2) void k_gemm8(const u16* __restrict__ A,
                                                  const u16* __restrict__ Bw, int K,
                                                  const float* __restrict__ bias,
                                                  const float* __restrict__ resid,
                                                  void* __restrict__ outp, int ldc,
                                                  int bmN) {
  extern __shared__ u16 lds_g[];
  // elem offsets: AH: 0+par*8192, AL: 16384+par*8192, BH: 32768+par*8192, BL: 49152+par*8192
  const int t = threadIdx.x;
  const int lane = t & 63;
  const int w = t >> 6;
  const int wm = w >> 2, wn = w & 3;  // 2 x 4 waves, wave tile 128x64
  const int rl = lane & 15;
  const int kq = lane >> 4;  // 16B chunk quarter within 32-K (ck = kk*4+kq within 64)
  // XCD-chunked block swizzle (grid %8==0 for all launches)
  const int nwg = gridDim.x;
  const int cpx = nwg >> 3;
  const int id = blockIdx.x;
  const int sid = (id & 7) * cpx + (id >> 3);
  const int bm = sid % bmN, bn = sid / bmN;

  const u16* Ag = A + (size_t)bm * 256 * K;
  const u16* Bg = Bw + (size_t)bn * 256 * K;
  u16* const SAm = lds_g + (wm ? 16384 : 0);                  // own A half (+par*8192)
  u16* const SBm = lds_g + 32768 + ((wn >> 1) ? 16384 : 0);   // own B half (+par*8192)
  const int rBl = (wn & 1) * 64;  // local N-row base within B half

  f32x4 acc[8][4] = {};

  // prologue: all 4 halves of tile 0 (8 loads/wave)
  stage_half128(Ag, K, lds_g + 0, t);
  stage_half128(Ag + (size_t)128 * K, K, lds_g + 16384, t);
  stage_half128(Bg, K, lds_g + 32768, t);
  stage_half128(Bg + (size_t)128 * K, K, lds_g + 49152, t);
  VM0;
  BARRIER;

  const int NT = K >> 6;
  for (int T = 0; T < NT; ++T) {
    const int par = T & 1, nx = par ^ 1;
    const bool hn = (T + 1 < NT);
    const u16* An = Ag + (size_t)(T + 1) * 64;
    const u16* Bn = Bg + (size_t)(T + 1) * 64;
    bf16x8 b[4][2];
#pragma unroll
    for (int p = 0; p < 4; ++p) {
      bf16x8 a[2][2];
#pragma unroll
      for (int rf = 0; rf < 2; ++rf)
#pragma unroll
        for (int kk = 0; kk < 2; ++kk)
          a[rf][kk] = ldsfrag64(SAm + par * 8192, p * 32 + rf * 16 + rl, kk * 4 + kq);
      if (p == 0) {
#pragma unroll
        for (int n = 0; n < 4; ++n)
#pragma unroll
          for (int kk = 0; kk < 2; ++kk)
            b[n][kk] = ldsfrag64(SBm + par * 8192, rBl + n * 16 + rl, kk * 4 + kq);
        if (hn) {
          stage_half128(An, K, lds_g + nx * 8192, t);
          stage_half128(Bn, K, lds_g + 32768 + nx * 8192, t);
        }
      } else if (p == 1) {
        if (hn) {
          stage_half128(An + (size_t)128 * K, K, lds_g + 16384 + nx * 8192, t);
          stage_half128(Bn + (size_t)128 * K, K, lds_g + 49152 + nx * 8192, t);
        }
      }
      BARRIER;
      LGKM0;
      __builtin_amdgcn_sched_barrier(0);
      __builtin_amdgcn_s_setprio(1);
#pragma unroll
      for (int rf = 0; rf < 2; ++rf)
#pragma unroll
        for (int n = 0; n < 4; ++n) {
          acc[p * 2 + rf][n] =
              __builtin_amdgcn_mfma_f32_16x16x32_bf16(a[rf][0], b[n][0], acc[p * 2 + rf][n], 0, 0, 0);
          acc[p * 2 + rf][n] =
              __builtin_amdgcn_mfma_f32_16x16x32_bf16(a[rf][1], b[n][1], acc[p * 2 + rf][n], 0, 0, 0);
        }
      __builtin_amdgcn_s_setprio(0);
      if (p == 3) VM0;  // once per tile; loads are >=2 phases old
      BARRIER;
    }
  }

  // epilogue: D layout col=lane&15, row=4*(lane>>4)+reg (m89-verified)
  const int rg = (lane >> 4) * 4;
  const int cl = lane & 15;
#pragma unroll
  for (int mi = 0; mi < 8; ++mi)
#pragma unroll
    for (int n = 0; n < 4; ++n) {
      const int mg = bm * 256 + wm * 128 + mi * 16 + rg;
      const int og = bn * 256 + wn * 64 + n * 16 + cl;
#pragma unroll
      for (int r = 0; r < 4; ++r) {
        float v = acc[mi][n][r];
        size_t idx = (size_t)(mg + r) * ldc + og;
        if (EPI == 0) {
          ((u16*)outp)[idx] = f2bf(v);
        } else if (EPI == 1) {
          ((float*)outp)[idx] = resid[idx] + v + bias[og];
        } else if (EPI == 2) {
          ((u16*)outp)[idx] = f2bf(fmaxf(v + bias[og], 0.f));
        } else {
          ((float*)outp)[idx] = ((float*)outp)[idx] + v + bias[og];
        }
      }
    }
}

// ---------------- Attention: one block per (region, head); 4 waves x 64 q-rows ----------------
__device__ __forceinline__ int swz(int row, int col) {
  return row * 64 + (col ^ ((row & 7) << 3));
}

__global__ __launch_bounds__(256) void k_attn(const u16* __restrict__ qkv,
                                              u16* __restrict__ attn) {
  __shared__ u16 Ks[64 * 64];
  __shared__ u16 Vt[64 * 64];
  __shared__ u16 Pl[4 * 64 * 64];
  const int t = threadIdx.x, lane = t & 63, w = t >> 6;
  const int region = blockIdx.x >> 3;
  const int h = blockIdx.x & 7;
  const size_t n0 = (size_t)region * CC;
  const int qb = w * 64;
  const int rl = lane & 15;
  const int kg = (lane >> 4) * 8;
  u16* Pw = Pl + w * 4096;

  bf16x8 aq[4][2];
#pragma unroll
  for (int f = 0; f < 4; ++f)
#pragma unroll
    for (int ks = 0; ks < 2; ++ks)
      aq[f][ks] = *(const bf16x8*)&qkv[(n0 + qb + f * 16 + rl) * 1536 + h * 64 + ks * 32 + kg];

  f32x4 oacc[4][4] = {};
  float mrun[4][4], lrun[4][4];
#pragma unroll
  for (int i = 0; i < 4; ++i)
#pragma unroll
    for (int j = 0; j < 4; ++j) { mrun[i][j] = -1e30f; lrun[i][j] = 0.f; }

  const int sr = t >> 2;
  const int sc = (t & 3) * 16;
  for (int kt = 0; kt < 4; ++kt) {
    if (kt) __syncthreads();
    {
      const u16* kp = &qkv[(n0 + kt * 64 + sr) * 1536 + 512 + h * 64 + sc];
      bf16x8 k0 = *(const bf16x8*)kp;
      bf16x8 k1 = *(const bf16x8*)(kp + 8);
      *(bf16x8*)&Ks[swz(sr, sc)] = k0;
      *(bf16x8*)&Ks[swz(sr, sc + 8)] = k1;
      const u16* vp = &qkv[(n0 + kt * 64 + sr) * 1536 + 1024 + h * 64 + sc];
      bf16x8 v0 = *(const bf16x8*)vp;
      bf16x8 v1 = *(const bf16x8*)(vp + 8);
#pragma unroll
      for (int i = 0; i < 8; ++i) Vt[swz(sc + i, sr)] = ((u16*)&v0)[i];
#pragma unroll
      for (int i = 0; i < 8; ++i) Vt[swz(sc + 8 + i, sr)] = ((u16*)&v1)[i];
    }
    __syncthreads();
    f32x4 sacc[4][4] = {};
#pragma unroll
    for (int ks = 0; ks < 2; ++ks) {
      bf16x8 bk[4];
#pragma unroll
      for (int f = 0; f < 4; ++f) bk[f] = *(const bf16x8*)&Ks[swz(f * 16 + rl, ks * 32 + kg)];
#pragma unroll
      for (int i = 0; i < 4; ++i)
#pragma unroll
        for (int j = 0; j < 4; ++j)
          sacc[i][j] = __builtin_amdgcn_mfma_f32_16x16x32_bf16(aq[i][ks], bk[j], sacc[i][j], 0, 0, 0);
    }
#pragma unroll
    for (int i = 0; i < 4; ++i)
#pragma unroll
      for (int j = 0; j < 4; ++j)
#pragma unroll
        for (int r = 0; r < 4; ++r) sacc[i][j][r] *= 0.125f;
#pragma unroll
    for (int i = 0; i < 4; ++i) {
#pragma unroll
      for (int r = 0; r < 4; ++r) {
        float v = fmaxf(fmaxf(sacc[i][0][r], sacc[i][1][r]), fmaxf(sacc[i][2][r], sacc[i][3][r]));
#pragma unroll
        for (int m = 1; m < 16; m <<= 1) v = fmaxf(v, __shfl_xor(v, m));
        float mnew = fmaxf(mrun[i][r], v);
        float fac = __expf(mrun[i][r] - mnew);
        mrun[i][r] = mnew;
        float ps = 0.f;
#pragma unroll
        for (int fn = 0; fn < 4; ++fn) {
          float p = __expf(sacc[i][fn][r] - mnew);
          sacc[i][fn][r] = p;
          ps += p;
        }
#pragma unroll
        for (int m = 1; m < 16; m <<= 1) ps += __shfl_xor(ps, m);
        lrun[i][r] = lrun[i][r] * fac + ps;
#pragma unroll
        for (int fd = 0; fd < 4; ++fd) oacc[i][fd][r] *= fac;
      }
#pragma unroll
      for (int fn = 0; fn < 4; ++fn)
#pragma unroll
        for (int r = 0; r < 4; ++r)
          Pw[swz(i * 16 + (lane >> 4) * 4 + r, fn * 16 + rl)] = f2bf(sacc[i][fn][r]);
    }
#pragma unroll
    for (int ks = 0; ks < 2; ++ks) {
      bf16x8 ap[4], bv[4];
#pragma unroll
      for (int f = 0; f < 4; ++f) ap[f] = *(const bf16x8*)&Pw[swz(f * 16 + rl, ks * 32 + kg)];
#pragma unroll
      for (int f = 0; f < 4; ++f) bv[f] = *(const bf16x8*)&Vt[swz(f * 16 + rl, ks * 32 + kg)];
#pragma unroll
      for (int i = 0; i < 4; ++i)
#pragma unroll
        for (int j = 0; j < 4; ++j)
          oacc[i][j] = __builtin_amdgcn_mfma_f32_16x16x32_bf16(ap[i], bv[j], oacc[i][j], 0, 0, 0);
    }
  }
#pragma unroll
  for (int i = 0; i < 4; ++i)
#pragma unroll
    for (int fd = 0; fd < 4; ++fd)
#pragma unroll
      for (int r = 0; r < 4; ++r) {
        float v = oacc[i][fd][r] / lrun[i][r];
        attn[(n0 + qb + i * 16 + (lane >> 4) * 4 + r) * 512 + h * 64 + fd * 16 + rl] = f2bf(v);
      }
}

// ---------------- host launch ----------------
extern "C" void kernel_launch(void* const* d_in, const int* in_sizes, int n_in,
                              void* d_out, int out_size, void* d_ws, size_t ws_size,
                              hipStream_t stream) {
  (void)in_sizes; (void)n_in; (void)out_size; (void)ws_size;
  const float* x   = (const float*)d_in[0];
  const float* Wq  = (const float*)d_in[1];
  const float* Wk  = (const float*)d_in[2];
  const float* Wv  = (const float*)d_in[3];
  const float* Wo  = (const float*)d_in[4];
  const float* bo  = (const float*)d_in[5];
  const float* W1  = (const float*)d_in[6];
  const float* b1  = (const float*)d_in[7];
  const float* W2  = (const float*)d_in[8];
  const float* b2  = (const float*)d_in[9];
  const float* g1  = (const float*)d_in[10];
  const float* be1 = (const float*)d_in[11];
  const float* g2  = (const float*)d_in[12];
  const float* be2 = (const float*)d_in[13];
  float* out = (float*)d_out;

  char* ws = (char*)d_ws;
  u16* wqkv = (u16*)(ws + 0);          // [1536][512] bf16
  u16* wo   = (u16*)(ws + 1572864);    // [512][512]
  u16* w1   = (u16*)(ws + 2097152);    // [2048][512]
  u16* w2   = (u16*)(ws + 4194304);    // [512][2048]
  u16* regA = (u16*)(ws + 6291456);    // [N][512] bf16: h / attn / h2
  u16* regB = (u16*)(ws + 39845888);   // [N][1536] qkv, then [N][2048] ff

  const size_t LDSB = 131072;  // 128KB dynamic LDS for k_gemm8

  k_convall<<<1024, 256, 0, stream>>>(Wq, Wk, Wv, Wo, W1, W2, wqkv, wo, w1, w2);
  k_ln<<<NTOK / 4, 256, 0, stream>>>(x, g1, be1, regA);
  // QKV: [32768x512] x [1536x512]^T -> [N][1536]
  k_gemm8<0><<<dim3(128 * 6), 512, LDSB, stream>>>(regA, wqkv, 512, nullptr, nullptr, regB, 1536, 128);
  k_attn<<<dim3(4 * 32 * 8), 256, 0, stream>>>(regB, regA);
  // proj + bias + residual(x) -> out (f32)
  k_gemm8<1><<<dim3(128 * 2), 512, LDSB, stream>>>(regA, wo, 512, bo, x, out, 512, 128);
  k_ln<<<NTOK / 4, 256, 0, stream>>>(out, g2, be2, regA);
  // FFN1: relu(h2 * w1^T + b1) -> [N][2048]
  k_gemm8<2><<<dim3(128 * 8), 512, LDSB, stream>>>(regA, w1, 512, b1, nullptr, regB, 2048, 128);
  // FFN2: out += ff * w2^T + b2
  k_gemm8<3><<<dim3(128 * 2), 512, LDSB, stream>>>(regB, w2, 2048, b2, nullptr, out, 512, 128);
}